// Round 1
// baseline (2301.501 us; speedup 1.0000x reference)
//
#include <hip/hip_runtime.h>

typedef unsigned short u16;
typedef unsigned int   u32;
typedef __attribute__((ext_vector_type(8))) __bf16 bf16x8;
typedef __attribute__((ext_vector_type(4))) float  f32x4;

#define DEVI __device__ __forceinline__

// ---- dims ----
#define BB   4
#define TT   4096
#define DD   2048
#define DZ   512
#define NL   64      // latents M
#define NH   16
#define DHD  128
#define DFF  8192
#define ROWS (BB*TT) // 16384

DEVI u16 f2bf(float f) {
  u32 u = __float_as_uint(f);
  u32 r = (u + 0x7fffu + ((u >> 16) & 1u)) >> 16;
  return (u16)r;
}
DEVI u32 pack2(float a, float b) { return (u32)f2bf(a) | ((u32)f2bf(b) << 16); }

#define GLOAD16(G, L) __builtin_amdgcn_global_load_lds( \
    (const __attribute__((address_space(1))) void*)(G),  \
    (__attribute__((address_space(3))) void*)(L), 16, 0, 0)

// ---------------- LayerNorm + cast to bf16 ----------------
__global__ __launch_bounds__(256) void k_ln(const float* __restrict__ h,
                                            const float* __restrict__ g,
                                            const float* __restrict__ be,
                                            u16* __restrict__ out) {
  const int row = blockIdx.x, tid = threadIdx.x;
  const float4* h4 = (const float4*)(h + (size_t)row * DD);
  float4 x0 = h4[tid*2], x1 = h4[tid*2+1];
  float s1 = x0.x+x0.y+x0.z+x0.w + x1.x+x1.y+x1.z+x1.w;
  float s2 = x0.x*x0.x+x0.y*x0.y+x0.z*x0.z+x0.w*x0.w
           + x1.x*x1.x+x1.y*x1.y+x1.z*x1.z+x1.w*x1.w;
  #pragma unroll
  for (int o = 32; o > 0; o >>= 1) {
    s1 += __shfl_down(s1, o, 64);
    s2 += __shfl_down(s2, o, 64);
  }
  __shared__ float red[8];
  const int lane = tid & 63, wv = tid >> 6;
  if (lane == 0) { red[wv] = s1; red[4+wv] = s2; }
  __syncthreads();
  s1 = red[0]+red[1]+red[2]+red[3];
  s2 = red[4]+red[5]+red[6]+red[7];
  const float mu = s1 * (1.f/(float)DD);
  const float rstd = rsqrtf(s2 * (1.f/(float)DD) - mu*mu + 1e-5f);
  const float4* g4 = (const float4*)g;
  const float4* b4 = (const float4*)be;
  float4 ga = g4[tid*2], gb = g4[tid*2+1], ba = b4[tid*2], bb = b4[tid*2+1];
  uint4 o4;
  o4.x = pack2((x0.x-mu)*rstd*ga.x+ba.x, (x0.y-mu)*rstd*ga.y+ba.y);
  o4.y = pack2((x0.z-mu)*rstd*ga.z+ba.z, (x0.w-mu)*rstd*ga.w+ba.w);
  o4.z = pack2((x1.x-mu)*rstd*gb.x+bb.x, (x1.y-mu)*rstd*gb.y+bb.y);
  o4.w = pack2((x1.z-mu)*rstd*gb.z+bb.z, (x1.w-mu)*rstd*gb.w+bb.w);
  *(uint4*)(out + (size_t)row*DD + tid*8) = o4;
}

// ---------------- cast f32 [K,N] -> bf16 [N,K] (weights, one-time) ----------------
__global__ __launch_bounds__(256) void k_castT(const float* __restrict__ W,
                                               u16* __restrict__ Wt, int K, int N) {
  __shared__ float tile[32][33];
  const int n0 = blockIdx.x * 32, k0 = blockIdx.y * 32;
  const int tx = threadIdx.x, ty = threadIdx.y; // 32 x 8
  #pragma unroll
  for (int i = 0; i < 4; i++)
    tile[ty + 8*i][tx] = W[(size_t)(k0 + ty + 8*i) * N + n0 + tx];
  __syncthreads();
  #pragma unroll
  for (int i = 0; i < 4; i++)
    Wt[(size_t)(n0 + ty + 8*i) * K + k0 + tx] = f2bf(tile[tx][ty + 8*i]);
}

// ---------------- K/V projection (fp32, tiny: 256x512 @ 512x2048) ----------------
// TRANS=0: out[r][c] standard [B*NL][D].  TRANS=1: out [b][h][d][m] (V pre-transposed)
template<int TRANS>
__global__ __launch_bounds__(256) void k_kvproj(const float* __restrict__ z,
                                                const float* __restrict__ W,
                                                const float* __restrict__ bias,
                                                float* __restrict__ out) {
  __shared__ float zs[4*DZ];
  const int r0 = blockIdx.x * 4;
  const int c  = blockIdx.y * 256 + threadIdx.x;
  for (int i = threadIdx.x; i < 4*DZ; i += 256) zs[i] = z[(size_t)r0*DZ + i];
  __syncthreads();
  float a0=0.f, a1=0.f, a2=0.f, a3=0.f;
  #pragma unroll 8
  for (int k = 0; k < DZ; k++) {
    const float w = W[(size_t)k*DD + c];
    a0 += zs[k]*w; a1 += zs[DZ+k]*w; a2 += zs[2*DZ+k]*w; a3 += zs[3*DZ+k]*w;
  }
  const float bc = bias[c];
  float acc[4] = {a0+bc, a1+bc, a2+bc, a3+bc};
  #pragma unroll
  for (int i = 0; i < 4; i++) {
    const int r = r0 + i;
    if (TRANS == 0) {
      out[(size_t)r*DD + c] = acc[i];
    } else {
      const int b = r >> 6, m = r & 63, hh = c >> 7, d = c & 127;
      out[(((size_t)(b*NH + hh)*DHD + d)*NL + m)] = acc[i];
    }
  }
}

// ---------------- bf16 MFMA GEMM: C[M,N] = A[M,K] @ Bt[N,K]^T ----------------
// EPI 0: bias -> bf16 | 1: bias+gelu(erf) -> bf16 | 2: bias, out = h + tanh(a)*v (f32)
template<int EPI>
__global__ __launch_bounds__(256) void k_gemm(const u16* __restrict__ A,
                                              const u16* __restrict__ Bt,
                                              const float* __restrict__ bias,
                                              void* __restrict__ outp,
                                              const float* __restrict__ hres,
                                              const float* __restrict__ alpha_p,
                                              int N, int K) {
  __shared__ __align__(16) u16 As[128*32];
  __shared__ __align__(16) u16 Bs[128*32];
  const int tid = threadIdx.x;
  const int lane = tid & 63, wv = tid >> 6;
  const int wr = wv >> 1, wc = wv & 1;
  const int bm = blockIdx.y * 128, bn = blockIdx.x * 128;
  f32x4 acc[4][4] = {};
  const int ar = tid >> 2;
  const int ac = (tid & 3) * 8;
  const u16* Ag = A  + (size_t)(bm + ar) * K + ac;
  const u16* Bg = Bt + (size_t)(bn + ar) * K + ac;
  u16* Al = As + ar*32 + ac;
  u16* Bl = Bs + ar*32 + ac;
  const int rr = lane & 15;
  const int kg = (lane >> 4) * 8;

  for (int k0 = 0; k0 < K; k0 += 32) {
    GLOAD16(Ag + k0, Al);
    GLOAD16(Ag + k0 + (size_t)64*K, Al + 64*32);
    GLOAD16(Bg + k0, Bl);
    GLOAD16(Bg + k0 + (size_t)64*K, Bl + 64*32);
    __syncthreads();
    bf16x8 af[4], bf_[4];
    #pragma unroll
    for (int m = 0; m < 4; m++)
      af[m] = *(const bf16x8*)(As + (wr*64 + m*16 + rr)*32 + kg);
    #pragma unroll
    for (int n = 0; n < 4; n++)
      bf_[n] = *(const bf16x8*)(Bs + (wc*64 + n*16 + rr)*32 + kg);
    #pragma unroll
    for (int m = 0; m < 4; m++)
      #pragma unroll
      for (int n = 0; n < 4; n++)
        acc[m][n] = __builtin_amdgcn_mfma_f32_16x16x32_bf16(af[m], bf_[n], acc[m][n], 0, 0, 0);
    __syncthreads();
  }

  float ta = 0.f;
  if constexpr (EPI == 2) ta = tanhf(alpha_p[0]);
  const int r0 = bm + wr*64 + (lane >> 4) * 4;
  const int c0 = bn + wc*64 + rr;
  #pragma unroll
  for (int m = 0; m < 4; m++) {
    #pragma unroll
    for (int n = 0; n < 4; n++) {
      const int col = c0 + n*16;
      const float bc = bias[col];
      #pragma unroll
      for (int j = 0; j < 4; j++) {
        const size_t idx = (size_t)(r0 + m*16 + j) * N + col;
        float v = acc[m][n][j] + bc;
        if constexpr (EPI == 0) {
          ((u16*)outp)[idx] = f2bf(v);
        } else if constexpr (EPI == 1) {
          v = 0.5f * v * (1.f + erff(v * 0.70710678118654752f));
          ((u16*)outp)[idx] = f2bf(v);
        } else {
          ((float*)outp)[idx] = hres[idx] + ta * v;
        }
      }
    }
  }
}

// ---------------- fused cross-attention (per block: one (b,h), 64 t-rows) ----------------
__global__ __launch_bounds__(256) void k_attn(const u16* __restrict__ Q,
                                              const float* __restrict__ Kp,
                                              const float* __restrict__ Vt,
                                              u16* __restrict__ ctx) {
  // padded leading dims (+8 bf16) to break stride-256B/128B bank conflicts
  constexpr int QP = 136, VP = 72, PP = 72;
  __shared__ __align__(16) u16 Qs[64*QP];
  __shared__ __align__(16) u16 Ks[64*QP];
  __shared__ __align__(16) u16 Vs[128*VP];
  __shared__ __align__(16) u16 Ps[64*PP];
  const int tid = threadIdx.x, lane = tid & 63, wv = tid >> 6;
  const int tb = blockIdx.x, hh = blockIdx.y, b = blockIdx.z;
  const int t0 = tb * 64;

  { // stage Q tile [64][128] bf16 (copy)
    const int r = tid >> 2, c = (tid & 3) * 32;
    const uint4* src = (const uint4*)(Q + (size_t)(b*TT + t0 + r)*DD + hh*DHD + c);
    uint4* dst = (uint4*)(Qs + r*QP + c);
    #pragma unroll
    for (int i = 0; i < 4; i++) dst[i] = src[i];
  }
  { // stage K tile [64][128] f32->bf16
    const int m = tid >> 2, c = (tid & 3) * 32;
    const float4* src = (const float4*)(Kp + (size_t)(b*NL + m)*DD + hh*DHD + c);
    u16* dst = Ks + m*QP + c;
    #pragma unroll
    for (int i = 0; i < 8; i++) {
      float4 f = src[i];
      uint2 p; p.x = pack2(f.x, f.y); p.y = pack2(f.z, f.w);
      *(uint2*)(dst + i*4) = p;
    }
  }
  { // stage V^T tile [128 d][64 m] f32->bf16 (Vt already [b][h][d][m] contiguous)
    const float4* vsrc = (const float4*)(Vt + (size_t)(b*NH + hh)*DHD*NL);
    #pragma unroll
    for (int i = 0; i < 8; i++) {
      const int i4 = i*256 + tid;
      float4 f = vsrc[i4];
      const int d = i4 >> 4, m = (i4 & 15) * 4;
      uint2 p; p.x = pack2(f.x, f.y); p.y = pack2(f.z, f.w);
      *(uint2*)(Vs + d*VP + m) = p;
    }
  }
  __syncthreads();

  // ---- QK^T: scores[64 t][64 m], wave wv owns t-rows [wv*16, +16) ----
  const int rr = lane & 15;
  const int kg = (lane >> 4) * 8;
  f32x4 sc[4] = {};
  #pragma unroll
  for (int kc = 0; kc < 4; kc++) {
    bf16x8 aq = *(const bf16x8*)(Qs + (wv*16 + rr)*QP + kc*32 + kg);
    #pragma unroll
    for (int f = 0; f < 4; f++) {
      bf16x8 bk = *(const bf16x8*)(Ks + (f*16 + rr)*QP + kc*32 + kg);
      sc[f] = __builtin_amdgcn_mfma_f32_16x16x32_bf16(aq, bk, sc[f], 0, 0, 0);
    }
  }
  // ---- softmax over m (rows live in 16-lane groups, reg j) ----
  constexpr float scale = 0.08838834764831845f; // 1/sqrt(128)
  #pragma unroll
  for (int f = 0; f < 4; f++) sc[f] *= scale;
  float inv[4];
  #pragma unroll
  for (int j = 0; j < 4; j++) {
    float mx = fmaxf(fmaxf(sc[0][j], sc[1][j]), fmaxf(sc[2][j], sc[3][j]));
    #pragma unroll
    for (int o = 1; o < 16; o <<= 1) mx = fmaxf(mx, __shfl_xor(mx, o, 64));
    float sum = 0.f;
    #pragma unroll
    for (int f = 0; f < 4; f++) { float p = __expf(sc[f][j] - mx); sc[f][j] = p; sum += p; }
    #pragma unroll
    for (int o = 1; o < 16; o <<= 1) sum += __shfl_xor(sum, o, 64);
    inv[j] = 1.f / sum;
  }
  // ---- write unnormalized P to LDS (transpose to A-frag layout) ----
  const int prow = wv*16 + (lane >> 4) * 4;
  #pragma unroll
  for (int j = 0; j < 4; j++)
    #pragma unroll
    for (int f = 0; f < 4; f++)
      Ps[(prow + j)*PP + f*16 + rr] = f2bf(sc[f][j]);

  // ---- PV: ctx[16 t][128 d] per wave ----
  f32x4 cv[8] = {};
  #pragma unroll
  for (int ks = 0; ks < 2; ks++) {
    bf16x8 ap = *(const bf16x8*)(Ps + (wv*16 + rr)*PP + ks*32 + kg);
    #pragma unroll
    for (int n = 0; n < 8; n++) {
      bf16x8 bv = *(const bf16x8*)(Vs + (n*16 + rr)*VP + ks*32 + kg);
      cv[n] = __builtin_amdgcn_mfma_f32_16x16x32_bf16(ap, bv, cv[n], 0, 0, 0);
    }
  }
  // ---- normalize + write ctx bf16 ----
  #pragma unroll
  for (int n = 0; n < 8; n++)
    #pragma unroll
    for (int j = 0; j < 4; j++) {
      const size_t row = (size_t)(b*TT + t0 + wv*16 + (lane >> 4)*4 + j);
      ctx[row*DD + hh*DHD + n*16 + rr] = f2bf(cv[n][j] * inv[j]);
    }
}

// ---------------- workspace layout (bytes) ----------------
#define OFF_LN   ((size_t)0)                      // h_ln bf16 (67,108,864) -> reused as ctx
#define OFF_W1T  ((size_t)67108864)               // 33,554,432
#define OFF_W2T  ((size_t)100663296)              // 33,554,432
#define OFF_BIG  ((size_t)134217728)              // 268,435,456 (ffn1 overwrites below)
#define OFF_WQT  (OFF_BIG)                        //  8,388,608
#define OFF_KP   (OFF_BIG + 8388608)              //  2,097,152
#define OFF_VT   (OFF_BIG + 10485760)             //  2,097,152
#define OFF_Q    (OFF_BIG + 12582912)             // 67,108,864
#define OFF_FFN1 (OFF_BIG)

extern "C" void kernel_launch(void* const* d_in, const int* in_sizes, int n_in,
                              void* d_out, int out_size, void* d_ws, size_t ws_size,
                              hipStream_t stream) {
  (void)in_sizes; (void)n_in; (void)out_size; (void)ws_size;
  const float* h     = (const float*)d_in[0];
  const float* z     = (const float*)d_in[1];
  const float* ln_g  = (const float*)d_in[2];
  const float* ln_b  = (const float*)d_in[3];
  const float* Wq    = (const float*)d_in[4];
  const float* bq    = (const float*)d_in[5];
  const float* Wk    = (const float*)d_in[6];
  const float* bk    = (const float*)d_in[7];
  const float* Wv    = (const float*)d_in[8];
  const float* bv    = (const float*)d_in[9];
  const float* W1    = (const float*)d_in[10];
  const float* b1    = (const float*)d_in[11];
  const float* W2    = (const float*)d_in[12];
  const float* b2    = (const float*)d_in[13];
  const float* alpha = (const float*)d_in[14];

  char* ws = (char*)d_ws;
  u16*   hln  = (u16*)(ws + OFF_LN);
  u16*   w1T  = (u16*)(ws + OFF_W1T);
  u16*   w2T  = (u16*)(ws + OFF_W2T);
  u16*   wqT  = (u16*)(ws + OFF_WQT);
  float* kp   = (float*)(ws + OFF_KP);
  float* vt   = (float*)(ws + OFF_VT);
  u16*   qb   = (u16*)(ws + OFF_Q);
  u16*   ctx  = (u16*)(ws + OFF_LN);    // reuse: h_ln dead after Q projection
  u16*   ffn1 = (u16*)(ws + OFF_FFN1);  // reuse: wqT/kp/vt/qb dead after attention

  dim3 b256(256), b32x8(32, 8);

  k_ln<<<ROWS, b256, 0, stream>>>(h, ln_g, ln_b, hln);
  k_castT<<<dim3(DD/32,  DD/32),  b32x8, 0, stream>>>(Wq, wqT, DD,  DD);
  k_castT<<<dim3(DFF/32, DD/32),  b32x8, 0, stream>>>(W1, w1T, DD,  DFF);
  k_castT<<<dim3(DD/32,  DFF/32), b32x8, 0, stream>>>(W2, w2T, DFF, DD);
  k_kvproj<0><<<dim3(BB*NL/4, DD/256), b256, 0, stream>>>(z, Wk, bk, kp);
  k_kvproj<1><<<dim3(BB*NL/4, DD/256), b256, 0, stream>>>(z, Wv, bv, vt);
  // Q = h_ln @ Wq + bq
  k_gemm<0><<<dim3(DD/128, ROWS/128), b256, 0, stream>>>(hln, wqT, bq, qb, nullptr, nullptr, DD, DD);
  // attention -> ctx
  k_attn<<<dim3(TT/64, NH, BB), b256, 0, stream>>>(qb, kp, vt, ctx);
  // ffn1 = gelu(ctx @ W1 + b1)
  k_gemm<1><<<dim3(DFF/128, ROWS/128), b256, 0, stream>>>(ctx, w1T, b1, ffn1, nullptr, nullptr, DFF, DD);
  // out = h + tanh(alpha) * (ffn1 @ W2 + b2)
  k_gemm<2><<<dim3(DD/128, ROWS/128), b256, 0, stream>>>(ffn1, w2T, b2, d_out, h, alpha, DD, DFF);
}

// Round 6
// 1822.767 us; speedup vs baseline: 1.2626x; 1.2626x over previous
//
#include <hip/hip_runtime.h>

typedef unsigned short u16;
typedef unsigned int   u32;
typedef __attribute__((ext_vector_type(8))) __bf16 bf16x8;
typedef __attribute__((ext_vector_type(4))) float  f32x4;

#define DEVI __device__ __forceinline__

// ---- dims ----
#define BB   4
#define TT   4096
#define DD   2048
#define DZ   512
#define NL   64      // latents M
#define NH   16
#define DHD  128
#define DFF  8192
#define ROWS (BB*TT) // 16384

DEVI u16 f2bf(float f) {
  u32 u = __float_as_uint(f);
  u32 r = (u + 0x7fffu + ((u >> 16) & 1u)) >> 16;
  return (u16)r;
}
DEVI u32 pack2(float a, float b) { return (u32)f2bf(a) | ((u32)f2bf(b) << 16); }

#define GLOAD16(G, L) __builtin_amdgcn_global_load_lds( \
    (const __attribute__((address_space(1))) void*)(G),  \
    (__attribute__((address_space(3))) void*)(L), 16, 0, 0)

// ---------------- LayerNorm + cast to bf16 ----------------
__global__ __launch_bounds__(256) void k_ln(const float* __restrict__ h,
                                            const float* __restrict__ g,
                                            const float* __restrict__ be,
                                            u16* __restrict__ out) {
  const int row = blockIdx.x, tid = threadIdx.x;
  const float4* h4 = (const float4*)(h + (size_t)row * DD);
  float4 x0 = h4[tid*2], x1 = h4[tid*2+1];
  float s1 = x0.x+x0.y+x0.z+x0.w + x1.x+x1.y+x1.z+x1.w;
  float s2 = x0.x*x0.x+x0.y*x0.y+x0.z*x0.z+x0.w*x0.w
           + x1.x*x1.x+x1.y*x1.y+x1.z*x1.z+x1.w*x1.w;
  #pragma unroll
  for (int o = 32; o > 0; o >>= 1) {
    s1 += __shfl_down(s1, o, 64);
    s2 += __shfl_down(s2, o, 64);
  }
  __shared__ float red[8];
  const int lane = tid & 63, wv = tid >> 6;
  if (lane == 0) { red[wv] = s1; red[4+wv] = s2; }
  __syncthreads();
  s1 = red[0]+red[1]+red[2]+red[3];
  s2 = red[4]+red[5]+red[6]+red[7];
  const float mu = s1 * (1.f/(float)DD);
  const float rstd = rsqrtf(s2 * (1.f/(float)DD) - mu*mu + 1e-5f);
  const float4* g4 = (const float4*)g;
  const float4* b4 = (const float4*)be;
  float4 ga = g4[tid*2], gb = g4[tid*2+1], ba = b4[tid*2], bb = b4[tid*2+1];
  uint4 o4;
  o4.x = pack2((x0.x-mu)*rstd*ga.x+ba.x, (x0.y-mu)*rstd*ga.y+ba.y);
  o4.y = pack2((x0.z-mu)*rstd*ga.z+ba.z, (x0.w-mu)*rstd*ga.w+ba.w);
  o4.z = pack2((x1.x-mu)*rstd*gb.x+bb.x, (x1.y-mu)*rstd*gb.y+bb.y);
  o4.w = pack2((x1.z-mu)*rstd*gb.z+bb.z, (x1.w-mu)*rstd*gb.w+bb.w);
  *(uint4*)(out + (size_t)row*DD + tid*8) = o4;
}

// ---------------- cast f32 [K,N] -> bf16 [N,K] (weights, one-time) ----------------
__global__ __launch_bounds__(256) void k_castT(const float* __restrict__ W,
                                               u16* __restrict__ Wt, int K, int N) {
  __shared__ float tile[32][33];
  const int n0 = blockIdx.x * 32, k0 = blockIdx.y * 32;
  const int tx = threadIdx.x, ty = threadIdx.y; // 32 x 8
  #pragma unroll
  for (int i = 0; i < 4; i++)
    tile[ty + 8*i][tx] = W[(size_t)(k0 + ty + 8*i) * N + n0 + tx];
  __syncthreads();
  #pragma unroll
  for (int i = 0; i < 4; i++)
    Wt[(size_t)(n0 + ty + 8*i) * K + k0 + tx] = f2bf(tile[tx][ty + 8*i]);
}

// ---------------- K/V projection (fp32, tiny: 256x512 @ 512x2048) ----------------
template<int TRANS>
__global__ __launch_bounds__(256) void k_kvproj(const float* __restrict__ z,
                                                const float* __restrict__ W,
                                                const float* __restrict__ bias,
                                                float* __restrict__ out) {
  __shared__ float zs[4*DZ];
  const int r0 = blockIdx.x * 4;
  const int c  = blockIdx.y * 256 + threadIdx.x;
  for (int i = threadIdx.x; i < 4*DZ; i += 256) zs[i] = z[(size_t)r0*DZ + i];
  __syncthreads();
  float a0=0.f, a1=0.f, a2=0.f, a3=0.f;
  #pragma unroll 8
  for (int k = 0; k < DZ; k++) {
    const float w = W[(size_t)k*DD + c];
    a0 += zs[k]*w; a1 += zs[DZ+k]*w; a2 += zs[2*DZ+k]*w; a3 += zs[3*DZ+k]*w;
  }
  const float bc = bias[c];
  float acc[4] = {a0+bc, a1+bc, a2+bc, a3+bc};
  #pragma unroll
  for (int i = 0; i < 4; i++) {
    const int r = r0 + i;
    if (TRANS == 0) {
      out[(size_t)r*DD + c] = acc[i];
    } else {
      const int b = r >> 6, m = r & 63, hh = c >> 7, d = c & 127;
      out[(((size_t)(b*NH + hh)*DHD + d)*NL + m)] = acc[i];
    }
  }
}

// ---------------- 256x256 bf16 MFMA GEMM, 3-buffer counted-vmcnt pipeline ----------
// C[M,N] = A[M,K] @ Bt[N,K]^T.  8 waves (2m x 4n), BK=32, LDS 3 x (A 16KB + B 16KB).
// T1: XCD-aware block swizzle. T2: 16B-granular XOR swizzle (both sides).
// T3/T4: stage tile t+2 while computing t; vmcnt(4) keeps 4 loads in flight.
// T5: setprio around MFMA cluster.
// EPI 0: bias -> bf16 | 1: bias+gelu(erf) -> bf16 | 2: bias, out = h + tanh(a)*v (f32)
template<int EPI>
__global__ __launch_bounds__(512, 2) void k_gemm(const u16* __restrict__ A,
                                                 const u16* __restrict__ Bt,
                                                 const float* __restrict__ bias,
                                                 void* __restrict__ outp,
                                                 const float* __restrict__ hres,
                                                 const float* __restrict__ alpha_p,
                                                 int N, int K, int gm) {
  __shared__ __align__(16) u16 lds[3 * 16384];   // 96 KB
  const int tid = threadIdx.x, lane = tid & 63, wv = tid >> 6;
  const int wm = wv >> 2, wn = wv & 3;
  // T1: XCD swizzle (grid counts are all %8==0); column-grouped within chunk
  const int nwg = gridDim.x;
  const int wg  = (blockIdx.x & 7) * (nwg >> 3) + (blockIdx.x >> 3);
  const int bm = (wg % gm) * 256, bn = (wg / gm) * 256;
  const int NT = K >> 5;

  // ---- staging addresses (per thread: 4 x 16B chunks per tile: A lo/hi, B lo/hi)
  const int so0 = tid * 16;              // LDS byte offset, rows 0..127 of tile
  const int sr0 = so0 >> 6;              // row 0..127 (row stride 64 B)
  // T2 swizzle on the *global source* (LDS dest stays linear): flip bits 4,5 by row bits 1,2
  const int scb = (so0 & 63) ^ ((sr0 & 2) << 3) ^ ((sr0 & 4) << 3);
  const u16* As0 = A  + (size_t)(bm + sr0)       * K + (scb >> 1);
  const u16* As1 = A  + (size_t)(bm + sr0 + 128) * K + (scb >> 1);
  const u16* Bs0 = Bt + (size_t)(bn + sr0)       * K + (scb >> 1);
  const u16* Bs1 = Bt + (size_t)(bn + sr0 + 128) * K + (scb >> 1);

#define STAGE(kt, b) do {                                   \
    const size_t ko_ = (size_t)(kt) * 32;                   \
    u16* la_ = lds + (b) * 16384 + tid * 8;                 \
    GLOAD16(As0 + ko_, la_);                                \
    GLOAD16(As1 + ko_, la_ + 4096);                         \
    GLOAD16(Bs0 + ko_, la_ + 8192);                         \
    GLOAD16(Bs1 + ko_, la_ + 12288);                        \
  } while (0)

  // ---- fragment read offsets (T2 swizzle folds into a per-lane constant)
  const int rr = lane & 15;
  const int kbe = ((((lane >> 4) << 4) ^ ((rr & 2) << 3) ^ ((rr & 4) << 3)) >> 1); // elems
  const int arow0 = wm * 128 + rr;   // + m*16
  const int brow0 = wn * 64 + rr;    // + n*16

  f32x4 acc[8][4] = {};

  STAGE(0, 0);
  STAGE(1, 1);
  asm volatile("s_waitcnt vmcnt(4)" ::: "memory");
  __builtin_amdgcn_s_barrier();
  __builtin_amdgcn_sched_barrier(0);

  int bcur = 0;
  for (int t = 0; t < NT; ++t) {
    int bn2 = bcur + 2; if (bn2 >= 3) bn2 -= 3;
    int ts = t + 2; if (ts >= NT) ts = 0;   // dummy re-stage keeps vmcnt uniform
    STAGE(ts, bn2);

    const u16* la = lds + bcur * 16384;
    const u16* lb = la + 8192;
    bf16x8 af[8], bfr[4];
    #pragma unroll
    for (int m = 0; m < 8; m++)
      af[m] = *(const bf16x8*)(la + (arow0 + m*16) * 32 + kbe);
    #pragma unroll
    for (int n = 0; n < 4; n++)
      bfr[n] = *(const bf16x8*)(lb + (brow0 + n*16) * 32 + kbe);

    __builtin_amdgcn_s_setprio(1);
    #pragma unroll
    for (int m = 0; m < 8; m++)
      #pragma unroll
      for (int n = 0; n < 4; n++)
        acc[m][n] = __builtin_amdgcn_mfma_f32_16x16x32_bf16(af[m], bfr[n], acc[m][n], 0, 0, 0);
    __builtin_amdgcn_s_setprio(0);

    asm volatile("s_waitcnt vmcnt(4)" ::: "memory"); // tile t+1 landed; t+2 in flight
    __builtin_amdgcn_s_barrier();
    __builtin_amdgcn_sched_barrier(0);
    bcur = (bcur + 1 == 3) ? 0 : bcur + 1;
  }
#undef STAGE

  // ---- epilogue ----
  float ta = 0.f;
  if constexpr (EPI == 2) ta = tanhf(alpha_p[0]);
  const int r0 = bm + wm * 128 + (lane >> 4) * 4;
  const int c0 = bn + wn * 64 + rr;
  #pragma unroll
  for (int m = 0; m < 8; m++) {
    #pragma unroll
    for (int n = 0; n < 4; n++) {
      const int col = c0 + n * 16;
      const float bc = bias[col];
      #pragma unroll
      for (int j = 0; j < 4; j++) {
        const size_t idx = (size_t)(r0 + m * 16 + j) * N + col;
        float v = acc[m][n][j] + bc;
        if constexpr (EPI == 0) {
          ((u16*)outp)[idx] = f2bf(v);
        } else if constexpr (EPI == 1) {
          v = 0.5f * v * (1.f + erff(v * 0.70710678118654752f));
          ((u16*)outp)[idx] = f2bf(v);
        } else {
          ((float*)outp)[idx] = hres[idx] + ta * v;
        }
      }
    }
  }
}

// ---------------- fused cross-attention (per block: one (b,h), 64 t-rows) ----------------
__global__ __launch_bounds__(256) void k_attn(const u16* __restrict__ Q,
                                              const float* __restrict__ Kp,
                                              const float* __restrict__ Vt,
                                              u16* __restrict__ ctx) {
  constexpr int QP = 136, VP = 72, PP = 72;
  __shared__ __align__(16) u16 Qs[64*QP];
  __shared__ __align__(16) u16 Ks[64*QP];
  __shared__ __align__(16) u16 Vs[128*VP];
  __shared__ __align__(16) u16 Ps[64*PP];
  const int tid = threadIdx.x, lane = tid & 63, wv = tid >> 6;
  const int tb = blockIdx.x, hh = blockIdx.y, b = blockIdx.z;
  const int t0 = tb * 64;

  {
    const int r = tid >> 2, c = (tid & 3) * 32;
    const uint4* src = (const uint4*)(Q + (size_t)(b*TT + t0 + r)*DD + hh*DHD + c);
    uint4* dst = (uint4*)(Qs + r*QP + c);
    #pragma unroll
    for (int i = 0; i < 4; i++) dst[i] = src[i];
  }
  {
    const int m = tid >> 2, c = (tid & 3) * 32;
    const float4* src = (const float4*)(Kp + (size_t)(b*NL + m)*DD + hh*DHD + c);
    u16* dst = Ks + m*QP + c;
    #pragma unroll
    for (int i = 0; i < 8; i++) {
      float4 f = src[i];
      uint2 p; p.x = pack2(f.x, f.y); p.y = pack2(f.z, f.w);
      *(uint2*)(dst + i*4) = p;
    }
  }
  {
    const float4* vsrc = (const float4*)(Vt + (size_t)(b*NH + hh)*DHD*NL);
    #pragma unroll
    for (int i = 0; i < 8; i++) {
      const int i4 = i*256 + tid;
      float4 f = vsrc[i4];
      const int d = i4 >> 4, m = (i4 & 15) * 4;
      uint2 p; p.x = pack2(f.x, f.y); p.y = pack2(f.z, f.w);
      *(uint2*)(Vs + d*VP + m) = p;
    }
  }
  __syncthreads();

  const int rr = lane & 15;
  const int kg = (lane >> 4) * 8;
  f32x4 sc[4] = {};
  #pragma unroll
  for (int kc = 0; kc < 4; kc++) {
    bf16x8 aq = *(const bf16x8*)(Qs + (wv*16 + rr)*QP + kc*32 + kg);
    #pragma unroll
    for (int f = 0; f < 4; f++) {
      bf16x8 bk = *(const bf16x8*)(Ks + (f*16 + rr)*QP + kc*32 + kg);
      sc[f] = __builtin_amdgcn_mfma_f32_16x16x32_bf16(aq, bk, sc[f], 0, 0, 0);
    }
  }
  constexpr float scale = 0.08838834764831845f; // 1/sqrt(128)
  #pragma unroll
  for (int f = 0; f < 4; f++) sc[f] *= scale;
  float inv[4];
  #pragma unroll
  for (int j = 0; j < 4; j++) {
    float mx = fmaxf(fmaxf(sc[0][j], sc[1][j]), fmaxf(sc[2][j], sc[3][j]));
    #pragma unroll
    for (int o = 1; o < 16; o <<= 1) mx = fmaxf(mx, __shfl_xor(mx, o, 64));
    float sum = 0.f;
    #pragma unroll
    for (int f = 0; f < 4; f++) { float p = __expf(sc[f][j] - mx); sc[f][j] = p; sum += p; }
    #pragma unroll
    for (int o = 1; o < 16; o <<= 1) sum += __shfl_xor(sum, o, 64);
    inv[j] = 1.f / sum;
  }
  const int prow = wv*16 + (lane >> 4) * 4;
  #pragma unroll
  for (int j = 0; j < 4; j++)
    #pragma unroll
    for (int f = 0; f < 4; f++)
      Ps[(prow + j)*PP + f*16 + rr] = f2bf(sc[f][j]);

  f32x4 cv[8] = {};
  #pragma unroll
  for (int ks = 0; ks < 2; ks++) {
    bf16x8 ap = *(const bf16x8*)(Ps + (wv*16 + rr)*PP + ks*32 + kg);
    #pragma unroll
    for (int n = 0; n < 8; n++) {
      bf16x8 bv = *(const bf16x8*)(Vs + (n*16 + rr)*VP + ks*32 + kg);
      cv[n] = __builtin_amdgcn_mfma_f32_16x16x32_bf16(ap, bv, cv[n], 0, 0, 0);
    }
  }
  #pragma unroll
  for (int n = 0; n < 8; n++)
    #pragma unroll
    for (int j = 0; j < 4; j++) {
      const size_t row = (size_t)(b*TT + t0 + wv*16 + (lane >> 4)*4 + j);
      ctx[row*DD + hh*DHD + n*16 + rr] = f2bf(cv[n][j] * inv[j]);
    }
}

// ---------------- workspace layout (bytes) ----------------
#define OFF_LN   ((size_t)0)
#define OFF_W1T  ((size_t)67108864)
#define OFF_W2T  ((size_t)100663296)
#define OFF_BIG  ((size_t)134217728)
#define OFF_WQT  (OFF_BIG)
#define OFF_KP   (OFF_BIG + 8388608)
#define OFF_VT   (OFF_BIG + 10485760)
#define OFF_Q    (OFF_BIG + 12582912)
#define OFF_FFN1 (OFF_BIG)

extern "C" void kernel_launch(void* const* d_in, const int* in_sizes, int n_in,
                              void* d_out, int out_size, void* d_ws, size_t ws_size,
                              hipStream_t stream) {
  (void)in_sizes; (void)n_in; (void)out_size; (void)ws_size;
  const float* h     = (const float*)d_in[0];
  const float* z     = (const float*)d_in[1];
  const float* ln_g  = (const float*)d_in[2];
  const float* ln_b  = (const float*)d_in[3];
  const float* Wq    = (const float*)d_in[4];
  const float* bq    = (const float*)d_in[5];
  const float* Wk    = (const float*)d_in[6];
  const float* bk    = (const float*)d_in[7];
  const float* Wv    = (const float*)d_in[8];
  const float* bv    = (const float*)d_in[9];
  const float* W1    = (const float*)d_in[10];
  const float* b1    = (const float*)d_in[11];
  const float* W2    = (const float*)d_in[12];
  const float* b2    = (const float*)d_in[13];
  const float* alpha = (const float*)d_in[14];

  char* ws = (char*)d_ws;
  u16*   hln  = (u16*)(ws + OFF_LN);
  u16*   w1T  = (u16*)(ws + OFF_W1T);
  u16*   w2T  = (u16*)(ws + OFF_W2T);
  u16*   wqT  = (u16*)(ws + OFF_WQT);
  float* kp   = (float*)(ws + OFF_KP);
  float* vt   = (float*)(ws + OFF_VT);
  u16*   qb   = (u16*)(ws + OFF_Q);
  u16*   ctx  = (u16*)(ws + OFF_LN);
  u16*   ffn1 = (u16*)(ws + OFF_FFN1);

  dim3 b256(256), b512(512), b32x8(32, 8);

  k_ln<<<ROWS, b256, 0, stream>>>(h, ln_g, ln_b, hln);
  k_castT<<<dim3(DD/32,  DD/32),  b32x8, 0, stream>>>(Wq, wqT, DD,  DD);
  k_castT<<<dim3(DFF/32, DD/32),  b32x8, 0, stream>>>(W1, w1T, DD,  DFF);
  k_castT<<<dim3(DD/32,  DFF/32), b32x8, 0, stream>>>(W2, w2T, DFF, DD);
  k_kvproj<0><<<dim3(BB*NL/4, DD/256), b256, 0, stream>>>(z, Wk, bk, kp);
  k_kvproj<1><<<dim3(BB*NL/4, DD/256), b256, 0, stream>>>(z, Wv, bv, vt);
  // Q = h_ln @ Wq + bq   (grid 64x8 = 512 blocks)
  k_gemm<0><<<dim3((ROWS/256)*(DD/256)), b512, 0, stream>>>(hln, wqT, bq, qb, nullptr, nullptr, DD, DD, ROWS/256);
  // attention -> ctx
  k_attn<<<dim3(TT/64, NH, BB), b256, 0, stream>>>(qb, kp, vt, ctx);
  // ffn1 = gelu(ctx @ W1 + b1)   (grid 64x32 = 2048 blocks)
  k_gemm<1><<<dim3((ROWS/256)*(DFF/256)), b512, 0, stream>>>(ctx, w1T, b1, ffn1, nullptr, nullptr, DFF, DD, ROWS/256);
  // out = h + tanh(alpha) * (ffn1 @ W2 + b2)   (grid 64x8 = 512 blocks)
  k_gemm<2><<<dim3((ROWS/256)*(DD/256)), b512, 0, stream>>>(ffn1, w2T, b2, d_out, h, alpha, DD, DFF, ROWS/256);
}

// Round 10
// 1668.120 us; speedup vs baseline: 1.3797x; 1.0927x over previous
//
#include <hip/hip_runtime.h>

typedef unsigned short u16;
typedef unsigned int   u32;
typedef __attribute__((ext_vector_type(8))) __bf16 bf16x8;
typedef __attribute__((ext_vector_type(4))) float  f32x4;

#define DEVI __device__ __forceinline__

// ---- dims ----
#define BB   4
#define TT   4096
#define DD   2048
#define DZ   512
#define NL   64      // latents M
#define NH   16
#define DHD  128
#define DFF  8192
#define ROWS (BB*TT) // 16384

DEVI u16 f2bf(float f) {
  u32 u = __float_as_uint(f);
  u32 r = (u + 0x7fffu + ((u >> 16) & 1u)) >> 16;
  return (u16)r;
}
DEVI u32 pack2(float a, float b) { return (u32)f2bf(a) | ((u32)f2bf(b) << 16); }

#define GLOAD16(G, L) __builtin_amdgcn_global_load_lds( \
    (const __attribute__((address_space(1))) void*)(G),  \
    (__attribute__((address_space(3))) void*)(L), 16, 0, 0)

// ---------------- LayerNorm + cast to bf16 ----------------
__global__ __launch_bounds__(256) void k_ln(const float* __restrict__ h,
                                            const float* __restrict__ g,
                                            const float* __restrict__ be,
                                            u16* __restrict__ out) {
  const int row = blockIdx.x, tid = threadIdx.x;
  const float4* h4 = (const float4*)(h + (size_t)row * DD);
  float4 x0 = h4[tid*2], x1 = h4[tid*2+1];
  float s1 = x0.x+x0.y+x0.z+x0.w + x1.x+x1.y+x1.z+x1.w;
  float s2 = x0.x*x0.x+x0.y*x0.y+x0.z*x0.z+x0.w*x0.w
           + x1.x*x1.x+x1.y*x1.y+x1.z*x1.z+x1.w*x1.w;
  #pragma unroll
  for (int o = 32; o > 0; o >>= 1) {
    s1 += __shfl_down(s1, o, 64);
    s2 += __shfl_down(s2, o, 64);
  }
  __shared__ float red[8];
  const int lane = tid & 63, wv = tid >> 6;
  if (lane == 0) { red[wv] = s1; red[4+wv] = s2; }
  __syncthreads();
  s1 = red[0]+red[1]+red[2]+red[3];
  s2 = red[4]+red[5]+red[6]+red[7];
  const float mu = s1 * (1.f/(float)DD);
  const float rstd = rsqrtf(s2 * (1.f/(float)DD) - mu*mu + 1e-5f);
  const float4* g4 = (const float4*)g;
  const float4* b4 = (const float4*)be;
  float4 ga = g4[tid*2], gb = g4[tid*2+1], ba = b4[tid*2], bb = b4[tid*2+1];
  uint4 o4;
  o4.x = pack2((x0.x-mu)*rstd*ga.x+ba.x, (x0.y-mu)*rstd*ga.y+ba.y);
  o4.y = pack2((x0.z-mu)*rstd*ga.z+ba.z, (x0.w-mu)*rstd*ga.w+ba.w);
  o4.z = pack2((x1.x-mu)*rstd*gb.x+bb.x, (x1.y-mu)*rstd*gb.y+bb.y);
  o4.w = pack2((x1.z-mu)*rstd*gb.z+bb.z, (x1.w-mu)*rstd*gb.w+bb.w);
  *(uint4*)(out + (size_t)row*DD + tid*8) = o4;
}

// ---------------- cast f32 [K,N] -> bf16 [N,K] (weights, one-time) ----------------
__global__ __launch_bounds__(256) void k_castT(const float* __restrict__ W,
                                               u16* __restrict__ Wt, int K, int N) {
  __shared__ float tile[32][33];
  const int n0 = blockIdx.x * 32, k0 = blockIdx.y * 32;
  const int tx = threadIdx.x, ty = threadIdx.y; // 32 x 8
  #pragma unroll
  for (int i = 0; i < 4; i++)
    tile[ty + 8*i][tx] = W[(size_t)(k0 + ty + 8*i) * N + n0 + tx];
  __syncthreads();
  #pragma unroll
  for (int i = 0; i < 4; i++)
    Wt[(size_t)(n0 + ty + 8*i) * K + k0 + tx] = f2bf(tile[tx][ty + 8*i]);
}

// ---------------- K/V projection (fp32, tiny: 256x512 @ 512x2048) ----------------
template<int TRANS>
__global__ __launch_bounds__(256) void k_kvproj(const float* __restrict__ z,
                                                const float* __restrict__ W,
                                                const float* __restrict__ bias,
                                                float* __restrict__ out) {
  __shared__ float zs[4*DZ];
  const int r0 = blockIdx.x * 4;
  const int c  = blockIdx.y * 256 + threadIdx.x;
  for (int i = threadIdx.x; i < 4*DZ; i += 256) zs[i] = z[(size_t)r0*DZ + i];
  __syncthreads();
  float a0=0.f, a1=0.f, a2=0.f, a3=0.f;
  #pragma unroll 8
  for (int k = 0; k < DZ; k++) {
    const float w = W[(size_t)k*DD + c];
    a0 += zs[k]*w; a1 += zs[DZ+k]*w; a2 += zs[2*DZ+k]*w; a3 += zs[3*DZ+k]*w;
  }
  const float bc = bias[c];
  float acc[4] = {a0+bc, a1+bc, a2+bc, a3+bc};
  #pragma unroll
  for (int i = 0; i < 4; i++) {
    const int r = r0 + i;
    if (TRANS == 0) {
      out[(size_t)r*DD + c] = acc[i];
    } else {
      const int b = r >> 6, m = r & 63, hh = c >> 7, d = c & 127;
      out[(((size_t)(b*NH + hh)*DHD + d)*NL + m)] = acc[i];
    }
  }
}

// ---------------- 256x256 bf16 MFMA GEMM, 2-buffer counted-vmcnt pipeline ----------
// C[M,N] = A[M,K] @ Bt[N,K]^T.  8 waves (2m x 4n), BK=32, LDS 2 x 32KB -> 2 blocks/CU.
// L2-patch scheduling: each XCD's 64 co-resident blocks form an 8x8 tile patch
// (8 A-panels + 8 B-panels hot instead of 1 B-panel + 64 A-panels).
// Per iter: ds_read frags(cur) -> lgkmcnt(0)+barrier -> STAGE(t+2 -> cur) -> MFMA
//           -> vmcnt(4)+barrier (tile t+1 landed; t+2 in flight; never drain to 0).
// EPI 0: bias -> bf16 | 1: bias+gelu(erf) -> bf16 | 2: bias, out = h + tanh(a)*v (f32)
template<int EPI>
__global__ __launch_bounds__(512, 2) void k_gemm(const u16* __restrict__ A,
                                                 const u16* __restrict__ Bt,
                                                 const float* __restrict__ bias,
                                                 void* __restrict__ outp,
                                                 const float* __restrict__ hres,
                                                 const float* __restrict__ alpha_p,
                                                 int N, int K, int gm) {
  __shared__ __align__(16) u16 lds[2 * 16384];   // 64 KB
  const int tid = threadIdx.x, lane = tid & 63, wv = tid >> 6;
  const int wm = wv >> 2, wn = wv & 3;
  // ---- XCD chunk + 8x8 patch ordering (bijective; gm%8==0 && gn%8==0 here) ----
  const int nwg = gridDim.x;
  const int gn  = nwg / gm;
  const int npr = gm >> 3;                 // patch rows
  const int npp = (npr * (gn >> 3)) >> 3;  // patches per XCD
  const int cid = blockIdx.x & 7;          // XCD id
  const int off = blockIdx.x >> 3;         // sequence within XCD
  const int q   = cid * npp + (off >> 6);  // global patch id (col-major over patches)
  const int w   = off & 63;                // position in 8x8 patch
  const int bm  = ((q % npr) * 8 + (w >> 3)) * 256;
  const int bn  = ((q / npr) * 8 + (w & 7)) * 256;
  const int NT  = K >> 5;

  // ---- staging addresses (per thread: 4 x 16B chunks per tile: A lo/hi, B lo/hi)
  const int so0 = tid * 16;              // LDS byte offset, rows 0..127 of tile
  const int sr0 = so0 >> 6;              // row 0..127 (row stride 64 B)
  // T2 swizzle on the *global source* (LDS dest stays linear): flip bits 4,5 by row bits 1,2
  const int scb = (so0 & 63) ^ ((sr0 & 2) << 3) ^ ((sr0 & 4) << 3);
  const u16* As0 = A  + (size_t)(bm + sr0)       * K + (scb >> 1);
  const u16* As1 = A  + (size_t)(bm + sr0 + 128) * K + (scb >> 1);
  const u16* Bs0 = Bt + (size_t)(bn + sr0)       * K + (scb >> 1);
  const u16* Bs1 = Bt + (size_t)(bn + sr0 + 128) * K + (scb >> 1);

#define STAGE(kt, b) do {                                   \
    const size_t ko_ = (size_t)(kt) * 32;                   \
    u16* la_ = lds + (b) * 16384 + tid * 8;                 \
    GLOAD16(As0 + ko_, la_);                                \
    GLOAD16(As1 + ko_, la_ + 4096);                         \
    GLOAD16(Bs0 + ko_, la_ + 8192);                         \
    GLOAD16(Bs1 + ko_, la_ + 12288);                        \
  } while (0)

  // ---- fragment read offsets (T2 swizzle folds into a per-lane constant)
  const int rr = lane & 15;
  const int kbe = ((((lane >> 4) << 4) ^ ((rr & 2) << 3) ^ ((rr & 4) << 3)) >> 1); // elems
  const int arow0 = wm * 128 + rr;   // + m*16
  const int brow0 = wn * 64 + rr;    // + n*16

  f32x4 acc[8][4] = {};

  STAGE(0, 0);
  STAGE(1, 1);
  asm volatile("s_waitcnt vmcnt(4)" ::: "memory");   // tile 0 landed; tile 1 in flight
  __builtin_amdgcn_s_barrier();
  __builtin_amdgcn_sched_barrier(0);

  int cur = 0;
  for (int t = 0; t < NT; ++t) {
    const u16* la = lds + cur * 16384;
    const u16* lb = la + 8192;
    bf16x8 af[8], bfr[4];
    #pragma unroll
    for (int m = 0; m < 8; m++)
      af[m] = *(const bf16x8*)(la + (arow0 + m*16) * 32 + kbe);
    #pragma unroll
    for (int n = 0; n < 4; n++)
      bfr[n] = *(const bf16x8*)(lb + (brow0 + n*16) * 32 + kbe);

    // all waves must finish reading buf[cur] before we overwrite it with tile t+2
    asm volatile("s_waitcnt lgkmcnt(0)" ::: "memory");
    __builtin_amdgcn_sched_barrier(0);
    __builtin_amdgcn_s_barrier();
    __builtin_amdgcn_sched_barrier(0);

    int ts = t + 2; if (ts >= NT) ts = 0;   // dummy re-stage keeps vmcnt uniform
    STAGE(ts, cur);

    __builtin_amdgcn_s_setprio(1);
    #pragma unroll
    for (int m = 0; m < 8; m++)
      #pragma unroll
      for (int n = 0; n < 4; n++)
        acc[m][n] = __builtin_amdgcn_mfma_f32_16x16x32_bf16(af[m], bfr[n], acc[m][n], 0, 0, 0);
    __builtin_amdgcn_s_setprio(0);

    asm volatile("s_waitcnt vmcnt(4)" ::: "memory"); // tile t+1 landed; t+2 in flight
    __builtin_amdgcn_s_barrier();
    __builtin_amdgcn_sched_barrier(0);
    cur ^= 1;
  }
#undef STAGE

  // ---- epilogue ----
  float ta = 0.f;
  if constexpr (EPI == 2) ta = tanhf(alpha_p[0]);
  const int r0 = bm + wm * 128 + (lane >> 4) * 4;
  const int c0 = bn + wn * 64 + rr;
  #pragma unroll
  for (int m = 0; m < 8; m++) {
    #pragma unroll
    for (int n = 0; n < 4; n++) {
      const int col = c0 + n * 16;
      const float bc = bias[col];
      #pragma unroll
      for (int j = 0; j < 4; j++) {
        const size_t idx = (size_t)(r0 + m * 16 + j) * N + col;
        float v = acc[m][n][j] + bc;
        if constexpr (EPI == 0) {
          ((u16*)outp)[idx] = f2bf(v);
        } else if constexpr (EPI == 1) {
          v = 0.5f * v * (1.f + erff(v * 0.70710678118654752f));
          ((u16*)outp)[idx] = f2bf(v);
        } else {
          ((float*)outp)[idx] = hres[idx] + ta * v;
        }
      }
    }
  }
}

// ---------------- fused cross-attention (per block: one (b,h), 64 t-rows) ----------------
__global__ __launch_bounds__(256) void k_attn(const u16* __restrict__ Q,
                                              const float* __restrict__ Kp,
                                              const float* __restrict__ Vt,
                                              u16* __restrict__ ctx) {
  constexpr int QP = 136, VP = 72, PP = 72;
  __shared__ __align__(16) u16 Qs[64*QP];
  __shared__ __align__(16) u16 Ks[64*QP];
  __shared__ __align__(16) u16 Vs[128*VP];
  __shared__ __align__(16) u16 Ps[64*PP];
  const int tid = threadIdx.x, lane = tid & 63, wv = tid >> 6;
  const int tb = blockIdx.x, hh = blockIdx.y, b = blockIdx.z;
  const int t0 = tb * 64;

  {
    const int r = tid >> 2, c = (tid & 3) * 32;
    const uint4* src = (const uint4*)(Q + (size_t)(b*TT + t0 + r)*DD + hh*DHD + c);
    uint4* dst = (uint4*)(Qs + r*QP + c);
    #pragma unroll
    for (int i = 0; i < 4; i++) dst[i] = src[i];
  }
  {
    const int m = tid >> 2, c = (tid & 3) * 32;
    const float4* src = (const float4*)(Kp + (size_t)(b*NL + m)*DD + hh*DHD + c);
    u16* dst = Ks + m*QP + c;
    #pragma unroll
    for (int i = 0; i < 8; i++) {
      float4 f = src[i];
      uint2 p; p.x = pack2(f.x, f.y); p.y = pack2(f.z, f.w);
      *(uint2*)(dst + i*4) = p;
    }
  }
  {
    const float4* vsrc = (const float4*)(Vt + (size_t)(b*NH + hh)*DHD*NL);
    #pragma unroll
    for (int i = 0; i < 8; i++) {
      const int i4 = i*256 + tid;
      float4 f = vsrc[i4];
      const int d = i4 >> 4, m = (i4 & 15) * 4;
      uint2 p; p.x = pack2(f.x, f.y); p.y = pack2(f.z, f.w);
      *(uint2*)(Vs + d*VP + m) = p;
    }
  }
  __syncthreads();

  const int rr = lane & 15;
  const int kg = (lane >> 4) * 8;
  f32x4 sc[4] = {};
  #pragma unroll
  for (int kc = 0; kc < 4; kc++) {
    bf16x8 aq = *(const bf16x8*)(Qs + (wv*16 + rr)*QP + kc*32 + kg);
    #pragma unroll
    for (int f = 0; f < 4; f++) {
      bf16x8 bk = *(const bf16x8*)(Ks + (f*16 + rr)*QP + kc*32 + kg);
      sc[f] = __builtin_amdgcn_mfma_f32_16x16x32_bf16(aq, bk, sc[f], 0, 0, 0);
    }
  }
  constexpr float scale = 0.08838834764831845f; // 1/sqrt(128)
  #pragma unroll
  for (int f = 0; f < 4; f++) sc[f] *= scale;
  float inv[4];
  #pragma unroll
  for (int j = 0; j < 4; j++) {
    float mx = fmaxf(fmaxf(sc[0][j], sc[1][j]), fmaxf(sc[2][j], sc[3][j]));
    #pragma unroll
    for (int o = 1; o < 16; o <<= 1) mx = fmaxf(mx, __shfl_xor(mx, o, 64));
    float sum = 0.f;
    #pragma unroll
    for (int f = 0; f < 4; f++) { float p = __expf(sc[f][j] - mx); sc[f][j] = p; sum += p; }
    #pragma unroll
    for (int o = 1; o < 16; o <<= 1) sum += __shfl_xor(sum, o, 64);
    inv[j] = 1.f / sum;
  }
  const int prow = wv*16 + (lane >> 4) * 4;
  #pragma unroll
  for (int j = 0; j < 4; j++)
    #pragma unroll
    for (int f = 0; f < 4; f++)
      Ps[(prow + j)*PP + f*16 + rr] = f2bf(sc[f][j]);

  f32x4 cv[8] = {};
  #pragma unroll
  for (int ks = 0; ks < 2; ks++) {
    bf16x8 ap = *(const bf16x8*)(Ps + (wv*16 + rr)*PP + ks*32 + kg);
    #pragma unroll
    for (int n = 0; n < 8; n++) {
      bf16x8 bv = *(const bf16x8*)(Vs + (n*16 + rr)*VP + ks*32 + kg);
      cv[n] = __builtin_amdgcn_mfma_f32_16x16x32_bf16(ap, bv, cv[n], 0, 0, 0);
    }
  }
  #pragma unroll
  for (int n = 0; n < 8; n++)
    #pragma unroll
    for (int j = 0; j < 4; j++) {
      const size_t row = (size_t)(b*TT + t0 + wv*16 + (lane >> 4)*4 + j);
      ctx[row*DD + hh*DHD + n*16 + rr] = f2bf(cv[n][j] * inv[j]);
    }
}

// ---------------- workspace layout (bytes) ----------------
#define OFF_LN   ((size_t)0)
#define OFF_W1T  ((size_t)67108864)
#define OFF_W2T  ((size_t)100663296)
#define OFF_BIG  ((size_t)134217728)
#define OFF_WQT  (OFF_BIG)
#define OFF_KP   (OFF_BIG + 8388608)
#define OFF_VT   (OFF_BIG + 10485760)
#define OFF_Q    (OFF_BIG + 12582912)
#define OFF_FFN1 (OFF_BIG)

extern "C" void kernel_launch(void* const* d_in, const int* in_sizes, int n_in,
                              void* d_out, int out_size, void* d_ws, size_t ws_size,
                              hipStream_t stream) {
  (void)in_sizes; (void)n_in; (void)out_size; (void)ws_size;
  const float* h     = (const float*)d_in[0];
  const float* z     = (const float*)d_in[1];
  const float* ln_g  = (const float*)d_in[2];
  const float* ln_b  = (const float*)d_in[3];
  const float* Wq    = (const float*)d_in[4];
  const float* bq    = (const float*)d_in[5];
  const float* Wk    = (const float*)d_in[6];
  const float* bk    = (const float*)d_in[7];
  const float* Wv    = (const float*)d_in[8];
  const float* bv    = (const float*)d_in[9];
  const float* W1    = (const float*)d_in[10];
  const float* b1    = (const float*)d_in[11];
  const float* W2    = (const float*)d_in[12];
  const float* b2    = (const float*)d_in[13];
  const float* alpha = (const float*)d_in[14];

  char* ws = (char*)d_ws;
  u16*   hln  = (u16*)(ws + OFF_LN);
  u16*   w1T  = (u16*)(ws + OFF_W1T);
  u16*   w2T  = (u16*)(ws + OFF_W2T);
  u16*   wqT  = (u16*)(ws + OFF_WQT);
  float* kp   = (float*)(ws + OFF_KP);
  float* vt   = (float*)(ws + OFF_VT);
  u16*   qb   = (u16*)(ws + OFF_Q);
  u16*   ctx  = (u16*)(ws + OFF_LN);
  u16*   ffn1 = (u16*)(ws + OFF_FFN1);

  dim3 b256(256), b512(512), b32x8(32, 8);

  k_ln<<<ROWS, b256, 0, stream>>>(h, ln_g, ln_b, hln);
  k_castT<<<dim3(DD/32,  DD/32),  b32x8, 0, stream>>>(Wq, wqT, DD,  DD);
  k_castT<<<dim3(DFF/32, DD/32),  b32x8, 0, stream>>>(W1, w1T, DD,  DFF);
  k_castT<<<dim3(DD/32,  DFF/32), b32x8, 0, stream>>>(W2, w2T, DFF, DD);
  k_kvproj<0><<<dim3(BB*NL/4, DD/256), b256, 0, stream>>>(z, Wk, bk, kp);
  k_kvproj<1><<<dim3(BB*NL/4, DD/256), b256, 0, stream>>>(z, Wv, bv, vt);
  // Q = h_ln @ Wq + bq   (grid 64x8 = 512 blocks)
  k_gemm<0><<<dim3((ROWS/256)*(DD/256)), b512, 0, stream>>>(hln, wqT, bq, qb, nullptr, nullptr, DD, DD, ROWS/256);
  // attention -> ctx
  k_attn<<<dim3(TT/64, NH, BB), b256, 0, stream>>>(qb, kp, vt, ctx);
  // ffn1 = gelu(ctx @ W1 + b1)   (grid 64x32 = 2048 blocks)
  k_gemm<1><<<dim3((ROWS/256)*(DFF/256)), b512, 0, stream>>>(ctx, w1T, b1, ffn1, nullptr, nullptr, DFF, DD, ROWS/256);
  // out = h + tanh(alpha) * (ffn1 @ W2 + b2)   (grid 64x8 = 512 blocks)
  k_gemm<2><<<dim3((ROWS/256)*(DD/256)), b512, 0, stream>>>(ffn1, w2T, b2, d_out, h, alpha, DD, DFF, ROWS/256);
}